// Round 15
// baseline (71.233 us; speedup 1.0000x reference)
//
#include <hip/hip_runtime.h>
#include <math.h>

constexpr int B = 16384;
constexpr int V = 8;
constexpr int J = 21;
constexpr int TOTAL = B * J;        // 344064
constexpr int HALF  = TOTAL / 2;    // 172032 = 2688 * 64

// ===== Numerical situation (established R1-R14) =====
// The f32 A-BUILD bitstream decides the last bf16 quantum at the worst
// element. PINNED with fmaf/__fmul_rn; five recompiles at absmax 4096
// (R10-R14). Solver-side f64 rounding invariant-safe. DO NOT change the
// A-build intrinsics or dehomog expressions.
//
// Perf: R12 41.3 -> R13 39.8 -> R14 35.5us. R14: VALUBusy 48%, occ 30%,
// HBM 10% => still latency-bound (~3 waves/SIMD over ~100cy f64 chains).
// This round: TWO problems per thread (t, t+HALF) -> ILP-4 on every
// chain link; per-problem instruction streams are IDENTICAL to R14's
// (bit-exact outputs by construction), only scheduling interleaves.

__device__ __forceinline__ double fast_rsqrt(double u) {
    double r = (double)__builtin_amdgcn_rsqf((float)u);
    double hu = -0.5 * u;
    r = r * fma(hu * r, r, 1.5);   // 1 Newton step: ~2e-13 rel (R14-verified)
    return r;
}

// One parallel Jacobi STAGE: two rotations on disjoint pairs (p,q),(r,s).
#define PSTAGE(app, aqq, apq, arr, ass, ars, ca, cb, cd, ce,               \
               v0p, v0q, v1p, v1q, v2p, v2q, v3p, v3q,                     \
               w0r, w0s, w1r, w1s, w2r, w2s, w3r, w3s)                     \
  {                                                                        \
    double dA_ = aqq - app;                                                \
    double uA_ = fma(dA_, dA_, 4.0 * (apq * apq));                         \
    double riA_ = fast_rsqrt(uA_);                                         \
    double c2A_ = fma(0.5 * fabs(dA_), riA_, 0.5);                         \
    double icA_ = fast_rsqrt(c2A_);                                        \
    double cA_ = c2A_ * icA_;                                              \
    double sA_ = ((dA_ >= 0.0) ? apq : -apq) * (riA_ * icA_);              \
    double tA_ = sA_ * icA_;                                               \
    bool zA_ = (apq == 0.0);                                               \
    cA_ = zA_ ? 1.0 : cA_; sA_ = zA_ ? 0.0 : sA_; tA_ = zA_ ? 0.0 : tA_;   \
    double dB_ = ass - arr;                                                \
    double uB_ = fma(dB_, dB_, 4.0 * (ars * ars));                         \
    double riB_ = fast_rsqrt(uB_);                                         \
    double c2B_ = fma(0.5 * fabs(dB_), riB_, 0.5);                         \
    double icB_ = fast_rsqrt(c2B_);                                        \
    double cB_ = c2B_ * icB_;                                              \
    double sB_ = ((dB_ >= 0.0) ? ars : -ars) * (riB_ * icB_);              \
    double tB_ = sB_ * icB_;                                               \
    bool zB_ = (ars == 0.0);                                               \
    cB_ = zB_ ? 1.0 : cB_; sB_ = zB_ ? 0.0 : sB_; tB_ = zB_ ? 0.0 : tB_;   \
    double tpA_ = tA_ * apq; app -= tpA_; aqq += tpA_; apq = 0.0;          \
    double tpB_ = tB_ * ars; arr -= tpB_; ass += tpB_; ars = 0.0;          \
    double a_ = ca, b_ = cb, d_ = cd, e_ = ce;                             \
    double a1_ = fma(cA_, a_, -sA_ * d_), d1_ = fma(sA_, a_, cA_ * d_);    \
    double b1_ = fma(cA_, b_, -sA_ * e_), e1_ = fma(sA_, b_, cA_ * e_);    \
    ca = fma(cB_, a1_, -sB_ * b1_); cb = fma(sB_, a1_, cB_ * b1_);         \
    cd = fma(cB_, d1_, -sB_ * e1_); ce = fma(sB_, d1_, cB_ * e1_);         \
    double x_, y_;                                                         \
    x_ = v0p; y_ = v0q; v0p = fma(cA_, x_, -sA_ * y_); v0q = fma(sA_, x_, cA_ * y_); \
    x_ = v1p; y_ = v1q; v1p = fma(cA_, x_, -sA_ * y_); v1q = fma(sA_, x_, cA_ * y_); \
    x_ = v2p; y_ = v2q; v2p = fma(cA_, x_, -sA_ * y_); v2q = fma(sA_, x_, cA_ * y_); \
    x_ = v3p; y_ = v3q; v3p = fma(cA_, x_, -sA_ * y_); v3q = fma(sA_, x_, cA_ * y_); \
    x_ = w0r; y_ = w0s; w0r = fma(cB_, x_, -sB_ * y_); w0s = fma(sB_, x_, cB_ * y_); \
    x_ = w1r; y_ = w1s; w1r = fma(cB_, x_, -sB_ * y_); w1s = fma(sB_, x_, cB_ * y_); \
    x_ = w2r; y_ = w2s; w2r = fma(cB_, x_, -sB_ * y_); w2s = fma(sB_, x_, cB_ * y_); \
    x_ = w3r; y_ = w3s; w3r = fma(cB_, x_, -sB_ * y_); w3s = fma(sB_, x_, cB_ * y_); \
  }

// A-build for one problem (suffix S), PINNED intrinsics (R10-R14-verified).
#define BUILD_M(S, bb, jj)                                                 \
  {                                                                        \
    for (int v = 0; v < V; ++v) {                                          \
        const float* Kp = intr + (size_t)((bb) * V + v) * 9;               \
        const float* Ep = extr + (size_t)((bb) * V + v) * 12;              \
        float K0 = Kp[0], K1 = Kp[1], K2 = Kp[2];                          \
        float K3 = Kp[3], K4 = Kp[4], K5 = Kp[5];                          \
        float K6 = Kp[6], K7 = Kp[7], K8 = Kp[8];                          \
        float P0[4], P1[4], P2[4];                                         \
        _Pragma("unroll")                                                  \
        for (int k = 0; k < 4; ++k) {                                      \
            float e0 = Ep[k], e1 = Ep[4 + k], e2 = Ep[8 + k];              \
            P0[k] = fmaf(K0, e0, fmaf(K1, e1, __fmul_rn(K2, e2)));         \
            P1[k] = fmaf(K3, e0, fmaf(K4, e1, __fmul_rn(K5, e2)));         \
            P2[k] = fmaf(K6, e0, fmaf(K7, e1, __fmul_rn(K8, e2)));         \
        }                                                                  \
        size_t uvbase = (size_t)((bb) * V + v) * J + (jj);                 \
        float uu = uv[uvbase * 2 + 0];                                     \
        float vv = uv[uvbase * 2 + 1];                                     \
        float w  = conf[uvbase];                                           \
        tw##S += w;                                                        \
        float r0[4], r1[4];                                                \
        _Pragma("unroll")                                                  \
        for (int k = 0; k < 4; ++k) {                                      \
            r0[k] = __fmul_rn(w, fmaf(uu, P2[k], -P0[k]));                 \
            r1[k] = __fmul_rn(w, fmaf(vv, P2[k], -P1[k]));                 \
        }                                                                  \
        m##S##00 += (double)r0[0] * r0[0] + (double)r1[0] * r1[0];         \
        m##S##01 += (double)r0[0] * r0[1] + (double)r1[0] * r1[1];         \
        m##S##02 += (double)r0[0] * r0[2] + (double)r1[0] * r1[2];         \
        m##S##03 += (double)r0[0] * r0[3] + (double)r1[0] * r1[3];         \
        m##S##11 += (double)r0[1] * r0[1] + (double)r1[1] * r1[1];         \
        m##S##12 += (double)r0[1] * r0[2] + (double)r1[1] * r1[2];         \
        m##S##13 += (double)r0[1] * r0[3] + (double)r1[1] * r1[3];         \
        m##S##22 += (double)r0[2] * r0[2] + (double)r1[2] * r1[2];         \
        m##S##23 += (double)r0[2] * r0[3] + (double)r1[2] * r1[3];         \
        m##S##33 += (double)r0[3] * r0[3] + (double)r1[3] * r1[3];         \
    }                                                                      \
  }

// One full cyclic sweep (3 parallel-pair stages) for problem suffix S.
#define SWEEP(S)                                                           \
    PSTAGE(m##S##00, m##S##11, m##S##01,  m##S##22, m##S##33, m##S##23,    \
           m##S##02, m##S##03, m##S##12, m##S##13,                         \
           v##S##00, v##S##01, v##S##10, v##S##11,                         \
           v##S##20, v##S##21, v##S##30, v##S##31,                         \
           v##S##02, v##S##03, v##S##12, v##S##13,                         \
           v##S##22, v##S##23, v##S##32, v##S##33);                        \
    PSTAGE(m##S##00, m##S##22, m##S##02,  m##S##11, m##S##33, m##S##13,    \
           m##S##01, m##S##03, m##S##12, m##S##23,                         \
           v##S##00, v##S##02, v##S##10, v##S##12,                         \
           v##S##20, v##S##22, v##S##30, v##S##32,                         \
           v##S##01, v##S##03, v##S##11, v##S##13,                         \
           v##S##21, v##S##23, v##S##31, v##S##33);                        \
    PSTAGE(m##S##00, m##S##33, m##S##03,  m##S##11, m##S##22, m##S##12,    \
           m##S##01, m##S##02, m##S##13, m##S##23,                         \
           v##S##00, v##S##03, v##S##10, v##S##13,                         \
           v##S##20, v##S##23, v##S##30, v##S##33,                         \
           v##S##01, v##S##02, v##S##11, v##S##12,                         \
           v##S##21, v##S##22, v##S##31, v##S##32);

// Eigenvector pick + dehomog (exact R1/R10 f32 expressions) + store.
#define FINISH(S, tt)                                                      \
  {                                                                        \
    double be = m##S##00;                                                  \
    double x0 = v##S##00, x1 = v##S##10, x2 = v##S##20, x3 = v##S##30;     \
    if (m##S##11 < be) { be = m##S##11; x0 = v##S##01; x1 = v##S##11; x2 = v##S##21; x3 = v##S##31; } \
    if (m##S##22 < be) { be = m##S##22; x0 = v##S##02; x1 = v##S##12; x2 = v##S##22; x3 = v##S##32; } \
    if (m##S##33 < be) { be = m##S##33; x0 = v##S##03; x1 = v##S##13; x2 = v##S##23; x3 = v##S##33; } \
    float xw = (float)x3;                                                  \
    bool valid = (tw##S > 0.1f) && (fabsf(xw) > 1e-6f);                    \
    float denom = xw + 1e-8f;                                              \
    float o0 = valid ? (float)x0 / denom : 0.0f;                           \
    float o1 = valid ? (float)x1 / denom : 0.0f;                           \
    float o2 = valid ? (float)x2 / denom : 0.0f;                           \
    out[(size_t)(tt) * 3 + 0] = o0;                                        \
    out[(size_t)(tt) * 3 + 1] = o1;                                        \
    out[(size_t)(tt) * 3 + 2] = o2;                                        \
  }

__global__ __launch_bounds__(64, 4)
void triangulate_kernel(const float* __restrict__ intr,   // (B,V,3,3)
                        const float* __restrict__ extr,   // (B,V,3,4)
                        const float* __restrict__ uv,     // (B,V,J,2)
                        const float* __restrict__ conf,   // (B,V,J)
                        float* __restrict__ out)          // (B,J,3)
{
    int t = blockIdx.x * blockDim.x + threadIdx.x;
    if (t >= HALF) return;
    int t0 = t;               // problem a
    int t1 = t + HALF;        // problem b (same j, b-index + 8192)
    int b0 = t0 / J, j0 = t0 - b0 * J;
    int b1 = t1 / J, j1 = t1 - b1 * J;

    double ma00 = 0, ma01 = 0, ma02 = 0, ma03 = 0;
    double ma11 = 0, ma12 = 0, ma13 = 0;
    double ma22 = 0, ma23 = 0, ma33 = 0;
    double mb00 = 0, mb01 = 0, mb02 = 0, mb03 = 0;
    double mb11 = 0, mb12 = 0, mb13 = 0;
    double mb22 = 0, mb23 = 0, mb33 = 0;
    float twa = 0.0f, twb = 0.0f;

    BUILD_M(a, b0, j0);
    BUILD_M(b, b1, j1);

    double va00 = 1, va01 = 0, va02 = 0, va03 = 0;
    double va10 = 0, va11 = 1, va12 = 0, va13 = 0;
    double va20 = 0, va21 = 0, va22 = 1, va23 = 0;
    double va30 = 0, va31 = 0, va32 = 0, va33 = 1;
    double vb00 = 1, vb01 = 0, vb02 = 0, vb03 = 0;
    double vb10 = 0, vb11 = 1, vb12 = 0, vb13 = 0;
    double vb20 = 0, vb21 = 0, vb22 = 1, vb23 = 0;
    double vb30 = 0, vb31 = 0, vb32 = 0, vb33 = 1;

    for (int sweep = 0; sweep < 8; ++sweep) {
        SWEEP(a);
        SWEEP(b);

        double off2a = ma01*ma01 + ma02*ma02 + ma03*ma03
                     + ma12*ma12 + ma13*ma13 + ma23*ma23;
        double tra = ma00 + ma11 + ma22 + ma33;
        double off2b = mb01*mb01 + mb02*mb02 + mb03*mb03
                     + mb12*mb12 + mb13*mb13 + mb23*mb23;
        double trb = mb00 + mb11 + mb22 + mb33;
        bool ok = (off2a <= 1e-26 * tra * tra) && (off2b <= 1e-26 * trb * trb);
        if (__all(ok)) break;
    }

    FINISH(a, t0);
    FINISH(b, t1);
}

extern "C" void kernel_launch(void* const* d_in, const int* in_sizes, int n_in,
                              void* d_out, int out_size, void* d_ws, size_t ws_size,
                              hipStream_t stream) {
    const float* intr = (const float*)d_in[0];
    const float* extr = (const float*)d_in[1];
    const float* uv   = (const float*)d_in[2];
    const float* conf = (const float*)d_in[3];
    float* out = (float*)d_out;

    int threads = HALF;                        // 172032
    int block = 64;
    int grid = (threads + block - 1) / block;  // 2688 (exact)
    triangulate_kernel<<<grid, block, 0, stream>>>(intr, extr, uv, conf, out);
}

// Round 16
// 41.996 us; speedup vs baseline: 1.6962x; 1.6962x over previous
//
#include <hip/hip_runtime.h>
#include <math.h>

constexpr int B = 16384;
constexpr int V = 8;
constexpr int J = 21;
constexpr int TOTAL = B * J;        // 344064
constexpr int HALF  = TOTAL / 2;    // 172032 = 2688 * 64

// ===== Numerical situation (established R1-R15) =====
// The f32 A-BUILD bitstream decides the last bf16 quantum at the worst
// element. PINNED with fmaf/__fmul_rn; six recompiles at absmax 4096
// (R10-R15). Solver-side f64 rounding invariant-safe. DO NOT change the
// A-build intrinsics or dehomog expressions.
//
// Perf: R14 35.5us (1 problem/thread, ILP-2, VALUBusy 48% latency-bound).
// R15 two-problems/thread PASSED at 4096 but спilled: __launch_bounds__
// (64,4) caps VGPR at 128 < the ~150 needed -> WRITE_SIZE 167MB, 71us.
// THIS ROUND: same R15 kernel, launch bounds (64,2) -> 256-VGPR budget.
// 2 waves/SIMD hard-resident (= measured effective occupancy anyway),
// each with ILP-4 on the f64 latency chains.

__device__ __forceinline__ double fast_rsqrt(double u) {
    double r = (double)__builtin_amdgcn_rsqf((float)u);
    double hu = -0.5 * u;
    r = r * fma(hu * r, r, 1.5);   // 1 Newton step: ~2e-13 rel (R14/R15-verified)
    return r;
}

// One parallel Jacobi STAGE: two rotations on disjoint pairs (p,q),(r,s).
#define PSTAGE(app, aqq, apq, arr, ass, ars, ca, cb, cd, ce,               \
               v0p, v0q, v1p, v1q, v2p, v2q, v3p, v3q,                     \
               w0r, w0s, w1r, w1s, w2r, w2s, w3r, w3s)                     \
  {                                                                        \
    double dA_ = aqq - app;                                                \
    double uA_ = fma(dA_, dA_, 4.0 * (apq * apq));                         \
    double riA_ = fast_rsqrt(uA_);                                         \
    double c2A_ = fma(0.5 * fabs(dA_), riA_, 0.5);                         \
    double icA_ = fast_rsqrt(c2A_);                                        \
    double cA_ = c2A_ * icA_;                                              \
    double sA_ = ((dA_ >= 0.0) ? apq : -apq) * (riA_ * icA_);              \
    double tA_ = sA_ * icA_;                                               \
    bool zA_ = (apq == 0.0);                                               \
    cA_ = zA_ ? 1.0 : cA_; sA_ = zA_ ? 0.0 : sA_; tA_ = zA_ ? 0.0 : tA_;   \
    double dB_ = ass - arr;                                                \
    double uB_ = fma(dB_, dB_, 4.0 * (ars * ars));                         \
    double riB_ = fast_rsqrt(uB_);                                         \
    double c2B_ = fma(0.5 * fabs(dB_), riB_, 0.5);                         \
    double icB_ = fast_rsqrt(c2B_);                                        \
    double cB_ = c2B_ * icB_;                                              \
    double sB_ = ((dB_ >= 0.0) ? ars : -ars) * (riB_ * icB_);              \
    double tB_ = sB_ * icB_;                                               \
    bool zB_ = (ars == 0.0);                                               \
    cB_ = zB_ ? 1.0 : cB_; sB_ = zB_ ? 0.0 : sB_; tB_ = zB_ ? 0.0 : tB_;   \
    double tpA_ = tA_ * apq; app -= tpA_; aqq += tpA_; apq = 0.0;          \
    double tpB_ = tB_ * ars; arr -= tpB_; ass += tpB_; ars = 0.0;          \
    double a_ = ca, b_ = cb, d_ = cd, e_ = ce;                             \
    double a1_ = fma(cA_, a_, -sA_ * d_), d1_ = fma(sA_, a_, cA_ * d_);    \
    double b1_ = fma(cA_, b_, -sA_ * e_), e1_ = fma(sA_, b_, cA_ * e_);    \
    ca = fma(cB_, a1_, -sB_ * b1_); cb = fma(sB_, a1_, cB_ * b1_);         \
    cd = fma(cB_, d1_, -sB_ * e1_); ce = fma(sB_, d1_, cB_ * e1_);         \
    double x_, y_;                                                         \
    x_ = v0p; y_ = v0q; v0p = fma(cA_, x_, -sA_ * y_); v0q = fma(sA_, x_, cA_ * y_); \
    x_ = v1p; y_ = v1q; v1p = fma(cA_, x_, -sA_ * y_); v1q = fma(sA_, x_, cA_ * y_); \
    x_ = v2p; y_ = v2q; v2p = fma(cA_, x_, -sA_ * y_); v2q = fma(sA_, x_, cA_ * y_); \
    x_ = v3p; y_ = v3q; v3p = fma(cA_, x_, -sA_ * y_); v3q = fma(sA_, x_, cA_ * y_); \
    x_ = w0r; y_ = w0s; w0r = fma(cB_, x_, -sB_ * y_); w0s = fma(sB_, x_, cB_ * y_); \
    x_ = w1r; y_ = w1s; w1r = fma(cB_, x_, -sB_ * y_); w1s = fma(sB_, x_, cB_ * y_); \
    x_ = w2r; y_ = w2s; w2r = fma(cB_, x_, -sB_ * y_); w2s = fma(sB_, x_, cB_ * y_); \
    x_ = w3r; y_ = w3s; w3r = fma(cB_, x_, -sB_ * y_); w3s = fma(sB_, x_, cB_ * y_); \
  }

// A-build for one problem (suffix S), PINNED intrinsics (R10-R15-verified).
#define BUILD_M(S, bb, jj)                                                 \
  {                                                                        \
    for (int v = 0; v < V; ++v) {                                          \
        const float* Kp = intr + (size_t)((bb) * V + v) * 9;               \
        const float* Ep = extr + (size_t)((bb) * V + v) * 12;              \
        float K0 = Kp[0], K1 = Kp[1], K2 = Kp[2];                          \
        float K3 = Kp[3], K4 = Kp[4], K5 = Kp[5];                          \
        float K6 = Kp[6], K7 = Kp[7], K8 = Kp[8];                          \
        float P0[4], P1[4], P2[4];                                         \
        _Pragma("unroll")                                                  \
        for (int k = 0; k < 4; ++k) {                                      \
            float e0 = Ep[k], e1 = Ep[4 + k], e2 = Ep[8 + k];              \
            P0[k] = fmaf(K0, e0, fmaf(K1, e1, __fmul_rn(K2, e2)));         \
            P1[k] = fmaf(K3, e0, fmaf(K4, e1, __fmul_rn(K5, e2)));         \
            P2[k] = fmaf(K6, e0, fmaf(K7, e1, __fmul_rn(K8, e2)));         \
        }                                                                  \
        size_t uvbase = (size_t)((bb) * V + v) * J + (jj);                 \
        float uu = uv[uvbase * 2 + 0];                                     \
        float vv = uv[uvbase * 2 + 1];                                     \
        float w  = conf[uvbase];                                           \
        tw##S += w;                                                        \
        float r0[4], r1[4];                                                \
        _Pragma("unroll")                                                  \
        for (int k = 0; k < 4; ++k) {                                      \
            r0[k] = __fmul_rn(w, fmaf(uu, P2[k], -P0[k]));                 \
            r1[k] = __fmul_rn(w, fmaf(vv, P2[k], -P1[k]));                 \
        }                                                                  \
        m##S##00 += (double)r0[0] * r0[0] + (double)r1[0] * r1[0];         \
        m##S##01 += (double)r0[0] * r0[1] + (double)r1[0] * r1[1];         \
        m##S##02 += (double)r0[0] * r0[2] + (double)r1[0] * r1[2];         \
        m##S##03 += (double)r0[0] * r0[3] + (double)r1[0] * r1[3];         \
        m##S##11 += (double)r0[1] * r0[1] + (double)r1[1] * r1[1];         \
        m##S##12 += (double)r0[1] * r0[2] + (double)r1[1] * r1[2];         \
        m##S##13 += (double)r0[1] * r0[3] + (double)r1[1] * r1[3];         \
        m##S##22 += (double)r0[2] * r0[2] + (double)r1[2] * r1[2];         \
        m##S##23 += (double)r0[2] * r0[3] + (double)r1[2] * r1[3];         \
        m##S##33 += (double)r0[3] * r0[3] + (double)r1[3] * r1[3];         \
    }                                                                      \
  }

// One full cyclic sweep (3 parallel-pair stages) for problem suffix S.
#define SWEEP(S)                                                           \
    PSTAGE(m##S##00, m##S##11, m##S##01,  m##S##22, m##S##33, m##S##23,    \
           m##S##02, m##S##03, m##S##12, m##S##13,                         \
           v##S##00, v##S##01, v##S##10, v##S##11,                         \
           v##S##20, v##S##21, v##S##30, v##S##31,                         \
           v##S##02, v##S##03, v##S##12, v##S##13,                         \
           v##S##22, v##S##23, v##S##32, v##S##33);                        \
    PSTAGE(m##S##00, m##S##22, m##S##02,  m##S##11, m##S##33, m##S##13,    \
           m##S##01, m##S##03, m##S##12, m##S##23,                         \
           v##S##00, v##S##02, v##S##10, v##S##12,                         \
           v##S##20, v##S##22, v##S##30, v##S##32,                         \
           v##S##01, v##S##03, v##S##11, v##S##13,                         \
           v##S##21, v##S##23, v##S##31, v##S##33);                        \
    PSTAGE(m##S##00, m##S##33, m##S##03,  m##S##11, m##S##22, m##S##12,    \
           m##S##01, m##S##02, m##S##13, m##S##23,                         \
           v##S##00, v##S##03, v##S##10, v##S##13,                         \
           v##S##20, v##S##23, v##S##30, v##S##33,                         \
           v##S##01, v##S##02, v##S##11, v##S##12,                         \
           v##S##21, v##S##22, v##S##31, v##S##32);

// Eigenvector pick + dehomog (exact R1/R10 f32 expressions) + store.
#define FINISH(S, tt)                                                      \
  {                                                                        \
    double be = m##S##00;                                                  \
    double x0 = v##S##00, x1 = v##S##10, x2 = v##S##20, x3 = v##S##30;     \
    if (m##S##11 < be) { be = m##S##11; x0 = v##S##01; x1 = v##S##11; x2 = v##S##21; x3 = v##S##31; } \
    if (m##S##22 < be) { be = m##S##22; x0 = v##S##02; x1 = v##S##12; x2 = v##S##22; x3 = v##S##32; } \
    if (m##S##33 < be) { be = m##S##33; x0 = v##S##03; x1 = v##S##13; x2 = v##S##23; x3 = v##S##33; } \
    float xw = (float)x3;                                                  \
    bool valid = (tw##S > 0.1f) && (fabsf(xw) > 1e-6f);                    \
    float denom = xw + 1e-8f;                                              \
    float o0 = valid ? (float)x0 / denom : 0.0f;                           \
    float o1 = valid ? (float)x1 / denom : 0.0f;                           \
    float o2 = valid ? (float)x2 / denom : 0.0f;                           \
    out[(size_t)(tt) * 3 + 0] = o0;                                        \
    out[(size_t)(tt) * 3 + 1] = o1;                                        \
    out[(size_t)(tt) * 3 + 2] = o2;                                        \
  }

__global__ __launch_bounds__(64, 2)   // 256-VGPR budget: the ONLY change vs R15
void triangulate_kernel(const float* __restrict__ intr,   // (B,V,3,3)
                        const float* __restrict__ extr,   // (B,V,3,4)
                        const float* __restrict__ uv,     // (B,V,J,2)
                        const float* __restrict__ conf,   // (B,V,J)
                        float* __restrict__ out)          // (B,J,3)
{
    int t = blockIdx.x * blockDim.x + threadIdx.x;
    if (t >= HALF) return;
    int t0 = t;               // problem a
    int t1 = t + HALF;        // problem b (same j, b-index + 8192)
    int b0 = t0 / J, j0 = t0 - b0 * J;
    int b1 = t1 / J, j1 = t1 - b1 * J;

    double ma00 = 0, ma01 = 0, ma02 = 0, ma03 = 0;
    double ma11 = 0, ma12 = 0, ma13 = 0;
    double ma22 = 0, ma23 = 0, ma33 = 0;
    double mb00 = 0, mb01 = 0, mb02 = 0, mb03 = 0;
    double mb11 = 0, mb12 = 0, mb13 = 0;
    double mb22 = 0, mb23 = 0, mb33 = 0;
    float twa = 0.0f, twb = 0.0f;

    BUILD_M(a, b0, j0);
    BUILD_M(b, b1, j1);

    double va00 = 1, va01 = 0, va02 = 0, va03 = 0;
    double va10 = 0, va11 = 1, va12 = 0, va13 = 0;
    double va20 = 0, va21 = 0, va22 = 1, va23 = 0;
    double va30 = 0, va31 = 0, va32 = 0, va33 = 1;
    double vb00 = 1, vb01 = 0, vb02 = 0, vb03 = 0;
    double vb10 = 0, vb11 = 1, vb12 = 0, vb13 = 0;
    double vb20 = 0, vb21 = 0, vb22 = 1, vb23 = 0;
    double vb30 = 0, vb31 = 0, vb32 = 0, vb33 = 1;

    for (int sweep = 0; sweep < 8; ++sweep) {
        SWEEP(a);
        SWEEP(b);

        double off2a = ma01*ma01 + ma02*ma02 + ma03*ma03
                     + ma12*ma12 + ma13*ma13 + ma23*ma23;
        double tra = ma00 + ma11 + ma22 + ma33;
        double off2b = mb01*mb01 + mb02*mb02 + mb03*mb03
                     + mb12*mb12 + mb13*mb13 + mb23*mb23;
        double trb = mb00 + mb11 + mb22 + mb33;
        bool ok = (off2a <= 1e-26 * tra * tra) && (off2b <= 1e-26 * trb * trb);
        if (__all(ok)) break;
    }

    FINISH(a, t0);
    FINISH(b, t1);
}

extern "C" void kernel_launch(void* const* d_in, const int* in_sizes, int n_in,
                              void* d_out, int out_size, void* d_ws, size_t ws_size,
                              hipStream_t stream) {
    const float* intr = (const float*)d_in[0];
    const float* extr = (const float*)d_in[1];
    const float* uv   = (const float*)d_in[2];
    const float* conf = (const float*)d_in[3];
    float* out = (float*)d_out;

    int threads = HALF;                        // 172032
    int block = 64;
    int grid = (threads + block - 1) / block;  // 2688 (exact)
    triangulate_kernel<<<grid, block, 0, stream>>>(intr, extr, uv, conf, out);
}

// Round 18
// 33.657 us; speedup vs baseline: 2.1165x; 1.2478x over previous
//
#include <hip/hip_runtime.h>
#include <math.h>

constexpr int B = 16384;
constexpr int V = 8;
constexpr int J = 21;

// ===== Numerical situation (established R1-R16) =====
// The f32 A-BUILD bitstream decides the last bf16 quantum at the worst
// element. PINNED with fmaf/__fmul_rn; seven recompiles at absmax 4096
// (R10-R16). Solver-side f64 rounding invariant-safe; exit 1e-18 ==
// exit 1e-30 bit-identical (R2 vs R3, direct test). DO NOT change the
// A-build intrinsics or dehomog expressions.
//
// Perf: R14 35.5us (1 prob/thread, parallel-pair, ILP-2) is the best
// balance; R15/R16 (2 probs/thread) lost TLP 1:1 with the ILP gain.
// This round (R17 fixed: macro-arg expansion via STAGE(OP) indirection):
// (a) 2 sweeps with f32 c,s (short chains) applied via the general f64
// 2x2 update (apq NOT zeroed -> M = V^T M0 V exact); (b) f64 polish to
// the proven 1e-18 exit.

__device__ __forceinline__ double fast_rsqrt(double u) {
    double r = (double)__builtin_amdgcn_rsqf((float)u);
    double hu = -0.5 * u;
    r = r * fma(hu * r, r, 1.5);   // 1 Newton step: ~2e-13 rel (R14-verified)
    return r;
}

// f64 parallel Jacobi stage (R14's PSTAGE, verbatim): exact c,s, zeroing ok.
#define PSTAGE(app, aqq, apq, arr, ass, ars, ca, cb, cd, ce,               \
               v0p, v0q, v1p, v1q, v2p, v2q, v3p, v3q,                     \
               w0r, w0s, w1r, w1s, w2r, w2s, w3r, w3s)                     \
  {                                                                        \
    double dA_ = aqq - app;                                                \
    double uA_ = fma(dA_, dA_, 4.0 * (apq * apq));                         \
    double riA_ = fast_rsqrt(uA_);                                         \
    double c2A_ = fma(0.5 * fabs(dA_), riA_, 0.5);                         \
    double icA_ = fast_rsqrt(c2A_);                                        \
    double cA_ = c2A_ * icA_;                                              \
    double sA_ = ((dA_ >= 0.0) ? apq : -apq) * (riA_ * icA_);              \
    double tA_ = sA_ * icA_;                                               \
    bool zA_ = (apq == 0.0);                                               \
    cA_ = zA_ ? 1.0 : cA_; sA_ = zA_ ? 0.0 : sA_; tA_ = zA_ ? 0.0 : tA_;   \
    double dB_ = ass - arr;                                                \
    double uB_ = fma(dB_, dB_, 4.0 * (ars * ars));                         \
    double riB_ = fast_rsqrt(uB_);                                         \
    double c2B_ = fma(0.5 * fabs(dB_), riB_, 0.5);                         \
    double icB_ = fast_rsqrt(c2B_);                                        \
    double cB_ = c2B_ * icB_;                                              \
    double sB_ = ((dB_ >= 0.0) ? ars : -ars) * (riB_ * icB_);              \
    double tB_ = sB_ * icB_;                                               \
    bool zB_ = (ars == 0.0);                                               \
    cB_ = zB_ ? 1.0 : cB_; sB_ = zB_ ? 0.0 : sB_; tB_ = zB_ ? 0.0 : tB_;   \
    double tpA_ = tA_ * apq; app -= tpA_; aqq += tpA_; apq = 0.0;          \
    double tpB_ = tB_ * ars; arr -= tpB_; ass += tpB_; ars = 0.0;          \
    double a_ = ca, b_ = cb, d_ = cd, e_ = ce;                             \
    double a1_ = fma(cA_, a_, -sA_ * d_), d1_ = fma(sA_, a_, cA_ * d_);    \
    double b1_ = fma(cA_, b_, -sA_ * e_), e1_ = fma(sA_, b_, cA_ * e_);    \
    ca = fma(cB_, a1_, -sB_ * b1_); cb = fma(sB_, a1_, cB_ * b1_);         \
    cd = fma(cB_, d1_, -sB_ * e1_); ce = fma(sB_, d1_, cB_ * e1_);         \
    double x_, y_;                                                         \
    x_ = v0p; y_ = v0q; v0p = fma(cA_, x_, -sA_ * y_); v0q = fma(sA_, x_, cA_ * y_); \
    x_ = v1p; y_ = v1q; v1p = fma(cA_, x_, -sA_ * y_); v1q = fma(sA_, x_, cA_ * y_); \
    x_ = v2p; y_ = v2q; v2p = fma(cA_, x_, -sA_ * y_); v2q = fma(sA_, x_, cA_ * y_); \
    x_ = v3p; y_ = v3q; v3p = fma(cA_, x_, -sA_ * y_); v3q = fma(sA_, x_, cA_ * y_); \
    x_ = w0r; y_ = w0s; w0r = fma(cB_, x_, -sB_ * y_); w0s = fma(sB_, x_, cB_ * y_); \
    x_ = w1r; y_ = w1s; w1r = fma(cB_, x_, -sB_ * y_); w1s = fma(sB_, x_, cB_ * y_); \
    x_ = w2r; y_ = w2s; w2r = fma(cB_, x_, -sB_ * y_); w2s = fma(sB_, x_, cB_ * y_); \
    x_ = w3r; y_ = w3s; w3r = fma(cB_, x_, -sB_ * y_); w3s = fma(sB_, x_, cB_ * y_); \
  }

// f32-coefficient stage: c,s from single-rsq f32 chains (short latency),
// applied in f64 with the GENERAL 2x2 update (apq NOT zeroed) so the
// invariant M = V^T M0 V holds to f64 eps. Convergence is then enforced
// by the f64 exit criterion exactly as in all passing rounds.
#define F32STAGE(app, aqq, apq, arr, ass, ars, ca, cb, cd, ce,             \
                 v0p, v0q, v1p, v1q, v2p, v2q, v3p, v3q,                   \
                 w0r, w0s, w1r, w1s, w2r, w2s, w3r, w3s)                   \
  {                                                                        \
    float dfA = (float)(aqq - app);                                        \
    float afA = (float)(apq);                                              \
    float ufA = fmaf(dfA, dfA, 4.0f * (afA * afA));                        \
    float riA = __builtin_amdgcn_rsqf(ufA);                                \
    float c2A = fmaf(0.5f * fabsf(dfA), riA, 0.5f);                        \
    float icA = __builtin_amdgcn_rsqf(c2A);                                \
    float cfA = c2A * icA;                                                 \
    float sfA = ((dfA >= 0.0f) ? afA : -afA) * (riA * icA);                \
    bool zA_ = (ufA < 1e-30f);                                             \
    double cA_ = zA_ ? 1.0 : (double)cfA;                                  \
    double sA_ = zA_ ? 0.0 : (double)sfA;                                  \
    float dfB = (float)(ass - arr);                                        \
    float afB = (float)(ars);                                              \
    float ufB = fmaf(dfB, dfB, 4.0f * (afB * afB));                        \
    float riB = __builtin_amdgcn_rsqf(ufB);                                \
    float c2B = fmaf(0.5f * fabsf(dfB), riB, 0.5f);                        \
    float icB = __builtin_amdgcn_rsqf(c2B);                                \
    float cfB = c2B * icB;                                                 \
    float sfB = ((dfB >= 0.0f) ? afB : -afB) * (riB * icB);                \
    bool zB_ = (ufB < 1e-30f);                                             \
    double cB_ = zB_ ? 1.0 : (double)cfB;                                  \
    double sB_ = zB_ ? 0.0 : (double)sfB;                                  \
    /* pair A: general symmetric 2x2 update, no zeroing */                 \
    double ccA = cA_ * cA_, ssA = sA_ * sA_, csA = cA_ * sA_;              \
    double d0A = app - aqq;                                                \
    double nppA = fma(ccA, app, fma(ssA, aqq, -2.0 * csA * apq));          \
    double nqqA = fma(ssA, app, fma(ccA, aqq,  2.0 * csA * apq));          \
    double npqA = fma(csA, d0A, (ccA - ssA) * apq);                        \
    app = nppA; aqq = nqqA; apq = npqA;                                    \
    /* pair B */                                                           \
    double ccB = cB_ * cB_, ssB = sB_ * sB_, csB = cB_ * sB_;              \
    double d0B = arr - ass;                                                \
    double nppB = fma(ccB, arr, fma(ssB, ass, -2.0 * csB * ars));          \
    double nqqB = fma(ssB, arr, fma(ccB, ass,  2.0 * csB * ars));          \
    double npqB = fma(csB, d0B, (ccB - ssB) * ars);                        \
    arr = nppB; ass = nqqB; ars = npqB;                                    \
    /* cross block: rot A then rot B (same as PSTAGE) */                   \
    double a_ = ca, b_ = cb, d_ = cd, e_ = ce;                             \
    double a1_ = fma(cA_, a_, -sA_ * d_), d1_ = fma(sA_, a_, cA_ * d_);    \
    double b1_ = fma(cA_, b_, -sA_ * e_), e1_ = fma(sA_, b_, cA_ * e_);    \
    ca = fma(cB_, a1_, -sB_ * b1_); cb = fma(sB_, a1_, cB_ * b1_);         \
    cd = fma(cB_, d1_, -sB_ * e1_); ce = fma(sB_, d1_, cB_ * e1_);         \
    double x_, y_;                                                         \
    x_ = v0p; y_ = v0q; v0p = fma(cA_, x_, -sA_ * y_); v0q = fma(sA_, x_, cA_ * y_); \
    x_ = v1p; y_ = v1q; v1p = fma(cA_, x_, -sA_ * y_); v1q = fma(sA_, x_, cA_ * y_); \
    x_ = v2p; y_ = v2q; v2p = fma(cA_, x_, -sA_ * y_); v2q = fma(sA_, x_, cA_ * y_); \
    x_ = v3p; y_ = v3q; v3p = fma(cA_, x_, -sA_ * y_); v3q = fma(sA_, x_, cA_ * y_); \
    x_ = w0r; y_ = w0s; w0r = fma(cB_, x_, -sB_ * y_); w0s = fma(sB_, x_, cB_ * y_); \
    x_ = w1r; y_ = w1s; w1r = fma(cB_, x_, -sB_ * y_); w1s = fma(sB_, x_, cB_ * y_); \
    x_ = w2r; y_ = w2s; w2r = fma(cB_, x_, -sB_ * y_); w2s = fma(sB_, x_, cB_ * y_); \
    x_ = w3r; y_ = w3s; w3r = fma(cB_, x_, -sB_ * y_); w3s = fma(sB_, x_, cB_ * y_); \
  }

// STAGE(OP) indirection: OP is the macro NAME; after substitution the
// rescan expands OP(...) with the full explicit argument list. (R17's
// F32STAGE(ARGS_STAGE1) failed: args are matched before expansion.)
#define STAGE1(OP) OP(m00, m11, m01,  m22, m33, m23,  m02, m03, m12, m13,  \
    v00, v01, v10, v11, v20, v21, v30, v31,                                \
    v02, v03, v12, v13, v22, v23, v32, v33)
#define STAGE2(OP) OP(m00, m22, m02,  m11, m33, m13,  m01, m03, m12, m23,  \
    v00, v02, v10, v12, v20, v22, v30, v32,                                \
    v01, v03, v11, v13, v21, v23, v31, v33)
#define STAGE3(OP) OP(m00, m33, m03,  m11, m22, m12,  m01, m02, m13, m23,  \
    v00, v03, v10, v13, v20, v23, v30, v33,                                \
    v01, v02, v11, v12, v21, v22, v31, v32)

__global__ __launch_bounds__(64, 4)
void triangulate_kernel(const float* __restrict__ intr,   // (B,V,3,3)
                        const float* __restrict__ extr,   // (B,V,3,4)
                        const float* __restrict__ uv,     // (B,V,J,2)
                        const float* __restrict__ conf,   // (B,V,J)
                        float* __restrict__ out)          // (B,J,3)
{
    int t = blockIdx.x * blockDim.x + threadIdx.x;
    if (t >= B * J) return;
    int b = t / J;
    int j = t - b * J;

    // ---- A-build in f32, contraction pattern PINNED (R10-R16):
    double m00 = 0, m01 = 0, m02 = 0, m03 = 0;
    double m11 = 0, m12 = 0, m13 = 0;
    double m22 = 0, m23 = 0;
    double m33 = 0;
    float total_w = 0.0f;

    for (int v = 0; v < V; ++v) {
        const float* Kp = intr + (size_t)(b * V + v) * 9;
        const float* Ep = extr + (size_t)(b * V + v) * 12;
        float K0 = Kp[0], K1 = Kp[1], K2 = Kp[2];
        float K3 = Kp[3], K4 = Kp[4], K5 = Kp[5];
        float K6 = Kp[6], K7 = Kp[7], K8 = Kp[8];

        float P0[4], P1[4], P2[4];
        #pragma unroll
        for (int k = 0; k < 4; ++k) {
            float e0 = Ep[k], e1 = Ep[4 + k], e2 = Ep[8 + k];
            P0[k] = fmaf(K0, e0, fmaf(K1, e1, __fmul_rn(K2, e2)));
            P1[k] = fmaf(K3, e0, fmaf(K4, e1, __fmul_rn(K5, e2)));
            P2[k] = fmaf(K6, e0, fmaf(K7, e1, __fmul_rn(K8, e2)));
        }

        size_t uvbase = (size_t)(b * V + v) * J + j;
        float uu = uv[uvbase * 2 + 0];
        float vv = uv[uvbase * 2 + 1];
        float w  = conf[uvbase];
        total_w += w;

        float r0[4], r1[4];
        #pragma unroll
        for (int k = 0; k < 4; ++k) {
            r0[k] = __fmul_rn(w, fmaf(uu, P2[k], -P0[k]));
            r1[k] = __fmul_rn(w, fmaf(vv, P2[k], -P1[k]));
        }

        m00 += (double)r0[0] * r0[0] + (double)r1[0] * r1[0];
        m01 += (double)r0[0] * r0[1] + (double)r1[0] * r1[1];
        m02 += (double)r0[0] * r0[2] + (double)r1[0] * r1[2];
        m03 += (double)r0[0] * r0[3] + (double)r1[0] * r1[3];
        m11 += (double)r0[1] * r0[1] + (double)r1[1] * r1[1];
        m12 += (double)r0[1] * r0[2] + (double)r1[1] * r1[2];
        m13 += (double)r0[1] * r0[3] + (double)r1[1] * r1[3];
        m22 += (double)r0[2] * r0[2] + (double)r1[2] * r1[2];
        m23 += (double)r0[2] * r0[3] + (double)r1[2] * r1[3];
        m33 += (double)r0[3] * r0[3] + (double)r1[3] * r1[3];
    }

    double v00 = 1, v01 = 0, v02 = 0, v03 = 0;
    double v10 = 0, v11 = 1, v12 = 0, v13 = 0;
    double v20 = 0, v21 = 0, v22 = 1, v23 = 0;
    double v30 = 0, v31 = 0, v32 = 0, v33 = 1;

    // ---- phase 1: two sweeps with f32 coefficients (short chains) ----
    STAGE1(F32STAGE);
    STAGE2(F32STAGE);
    STAGE3(F32STAGE);
    STAGE1(F32STAGE);
    STAGE2(F32STAGE);
    STAGE3(F32STAGE);

    // ---- phase 2: f64 polish sweeps to the proven exit criterion ----
    for (int sweep = 0; sweep < 8; ++sweep) {
        STAGE1(PSTAGE);
        STAGE2(PSTAGE);
        STAGE3(PSTAGE);

        double off2 = m01*m01 + m02*m02 + m03*m03
                    + m12*m12 + m13*m13 + m23*m23;
        double tr = m00 + m11 + m22 + m33;
        // 1e-18 == 1e-30 bit-identical on this dataset (R2 vs R3)
        if (__all(off2 <= 1e-18 * tr * tr)) break;
    }

    // ---- pick eigenvector of smallest eigenvalue ----
    double be = m00;
    double x0 = v00, x1 = v10, x2 = v20, x3 = v30;
    if (m11 < be) { be = m11; x0 = v01; x1 = v11; x2 = v21; x3 = v31; }
    if (m22 < be) { be = m22; x0 = v02; x1 = v12; x2 = v22; x3 = v32; }
    if (m33 < be) { be = m33; x0 = v03; x1 = v13; x2 = v23; x3 = v33; }

    // ---- dehomogenize: exact R1/R10 f32 expressions ----
    float xw = (float)x3;
    bool valid = (total_w > 0.1f) && (fabsf(xw) > 1e-6f);
    float denom = xw + 1e-8f;
    float o0 = valid ? (float)x0 / denom : 0.0f;
    float o1 = valid ? (float)x1 / denom : 0.0f;
    float o2 = valid ? (float)x2 / denom : 0.0f;

    out[(size_t)t * 3 + 0] = o0;
    out[(size_t)t * 3 + 1] = o1;
    out[(size_t)t * 3 + 2] = o2;
}

extern "C" void kernel_launch(void* const* d_in, const int* in_sizes, int n_in,
                              void* d_out, int out_size, void* d_ws, size_t ws_size,
                              hipStream_t stream) {
    const float* intr = (const float*)d_in[0];
    const float* extr = (const float*)d_in[1];
    const float* uv   = (const float*)d_in[2];
    const float* conf = (const float*)d_in[3];
    float* out = (float*)d_out;

    int total = B * J;                        // 344064
    int block = 64;
    int grid = (total + block - 1) / block;   // 5376 (exact)
    triangulate_kernel<<<grid, block, 0, stream>>>(intr, extr, uv, conf, out);
}